// Round 14
// baseline (317.338 us; speedup 1.0000x reference)
//
#include <hip/hip_runtime.h>
#include <hip/hip_bf16.h>

// ChebNet round 14 = round 13 resubmitted after GPU-acquisition infra failure.
//  - placement with EXACT XCD affinity at 4 edge passes: role encoded in low
//    bits of blockIdx (bid&4==0 -> placement, partition p=bid&3 on XCD p only;
//    bid&4!=0 -> proj on XCDs 4-7 only). Bucket lines stay in one L2.
//  - row histogram 8->4 partitions (same 100KB LDS as col): halves row passes.
// Gathers/mm2 as round 12. Algebra: out = P0 + L P1 + 2 L(L P2) - P2 + b;
// (Lz)[c] = -dis[c]*sum dis[r] z[r], dis folded into operands.

typedef unsigned short u16;

constexpr int N_    = 100000;
constexpr int E_    = 1600000;
constexpr int IN_   = 64;
constexpr int HID_  = 16;
constexpr int OUT_  = 40;
constexpr int CAP_  = 48;       // bucket capacity; Poisson(16) P(>=48)~6e-11/node
constexpr int S_    = 64;       // edge slices (EPS = 25000)
constexpr int EPS_  = E_ / S_;  // 25000
constexpr int P4_   = 4;        // partitions (row AND col), NPP4 = 25000 (100 KB)
constexpr int NPP4_ = N_ / P4_;
constexpr int NPAD_ = 100352;   // N padded to 1024 multiple
constexpr int PROJB_ = 1563;    // proj blocks (N*HID/1024 rounded up)

__device__ __forceinline__ float bf2f(u16 u) {
    return __uint_as_float((unsigned)u << 16);
}
__device__ __forceinline__ u16 f2bf(float x) {   // round-to-nearest-even
    unsigned u = __float_as_uint(x);
    return (u16)((u + 0x7FFFu + ((u >> 16) & 1u)) >> 16);
}

// ---- K1: col + row partitioned LDS histograms (4 partitions x 64 slices each) ----
// Layout: dst[(p*S_+s)*NPP4_] — must match reduce_all.
__global__ void __launch_bounds__(1024)
hist2(const int* __restrict__ row, const int* __restrict__ col,
      u16* __restrict__ prow, u16* __restrict__ pcol) {
    __shared__ int lds[NPP4_];   // 100 KB
    bool isCol = blockIdx.x < P4_ * S_;
    int b = isCol ? blockIdx.x : (blockIdx.x - P4_ * S_);
    const int* arr = isCol ? col : row;
    u16* dstbase = isCol ? pcol : prow;
    int p = b & 3, s = b >> 2;
    for (int i = threadIdx.x; i < NPP4_; i += 1024) lds[i] = 0;
    __syncthreads();
    int lo = p * NPP4_, e0 = s * EPS_;
    for (int i = threadIdx.x; i < EPS_; i += 1024) {
        int v = arr[e0 + i];
        unsigned d = (unsigned)(v - lo);
        if (d < (unsigned)NPP4_) atomicAdd(&lds[d], 1);
    }
    __syncthreads();
    u16* dst = dstbase + (size_t)(p * S_ + s) * NPP4_;
    for (int i = threadIdx.x; i < NPP4_; i += 1024) dst[i] = (u16)lds[i];
}

// ---- K2: dis = rsqrt(out-deg); pre[s][n] = excl slice-prefix of in-deg; indeg ----
__global__ void __launch_bounds__(1024)
reduce_all(const u16* __restrict__ prow, const u16* __restrict__ pcol,
           float* __restrict__ dis, u16* __restrict__ pre, int* __restrict__ indeg) {
    int n = blockIdx.x * 1024 + threadIdx.x;
    if (n >= N_) return;
    int p = n / NPP4_, i = n - p * NPP4_;
    {
        const u16* base = prow + (size_t)(p * S_) * NPP4_ + i;
        int d = 0;
#pragma unroll 8
        for (int s = 0; s < S_; ++s) d += base[(size_t)s * NPP4_];
        dis[n] = (d > 0) ? rsqrtf((float)d) : 0.0f;
    }
    {
        const u16* base = pcol + (size_t)(p * S_) * NPP4_ + i;
        int run = 0;
#pragma unroll 8
        for (int s = 0; s < S_; ++s) {
            pre[(size_t)s * NPAD_ + n] = (u16)run;
            run += base[(size_t)s * NPP4_];
        }
        indeg[n] = run;
    }
}

// ---- K3: placement (XCD-exclusive) + dense projection (XCDs 4-7) ----
// bid&4==0: placement, p=bid&3 -> XCD p (bid&7==p); s=bid>>3, skip s>=64.
// bid&4!=0: proj j=(bid>>3)*4+(bid&3) -> XCDs 4-7 only.
__global__ void __launch_bounds__(1024)
place_proj(const int* __restrict__ row, const int* __restrict__ col,
           const float* __restrict__ x, const float* __restrict__ W,
           const float* __restrict__ dis, const u16* __restrict__ pre,
           int* __restrict__ bucket,
           float* __restrict__ P0f, float* __restrict__ P2f,
           u16* __restrict__ A1, u16* __restrict__ A2) {
    __shared__ int pos[NPP4_];          // 100 KB (place role; proj aliases w)
    float* w = (float*)pos;             // proj role: 12 KB of the same LDS
    if ((blockIdx.x & 4) == 0) {
        int s = (int)(blockIdx.x >> 3);
        if (s >= S_) return;            // filler slot
        int p = blockIdx.x & 3;         // XCD p exclusively
        int lo = p * NPP4_, e0 = s * EPS_;
        const u16* psrc = pre + (size_t)s * NPAD_ + lo;
        for (int i = threadIdx.x; i < NPP4_; i += 1024) pos[i] = psrc[i];
        __syncthreads();
        for (int i = threadIdx.x; i < EPS_; i += 1024) {
            int c = col[e0 + i];
            unsigned d = (unsigned)(c - lo);
            if (d < (unsigned)NPP4_) {
                int r = row[e0 + i];
                int q = atomicAdd(&pos[d], 1);          // LDS atomic only
                if (q < CAP_) bucket[(size_t)c * CAP_ + q] = r;
            }
        }
    } else {
        int j = (int)(blockIdx.x >> 3) * 4 + (int)(blockIdx.x & 3);
        if (j >= PROJB_) return;
        for (int i = threadIdx.x; i < 3 * IN_ * HID_; i += 1024) w[i] = W[i];
        __syncthreads();
        int t = j * 1024 + threadIdx.x;
        if (t >= N_ * HID_) return;
        int n = t >> 4, jj = t & 15;
        const float* xr = x + (size_t)n * IN_;
        float a0 = 0.f, a1 = 0.f, a2 = 0.f;
#pragma unroll
        for (int i = 0; i < IN_; ++i) {
            float xv = xr[i];
            a0 += xv * w[i * 16 + jj];
            a1 += xv * w[1024 + i * 16 + jj];
            a2 += xv * w[2048 + i * 16 + jj];
        }
        float dn = dis[n];
        P0f[t] = a0;
        P2f[t] = a2;
        A1[t] = f2bf(dn * a1);
        A2[t] = f2bf(dn * a2);
    }
}

// ---- K4: 32-wide gather, 4 nodes/wave, latency-batched ----
__global__ void g32b(const u16* __restrict__ A1, const u16* __restrict__ A2,
                     const int* __restrict__ indeg, const int* __restrict__ bucket,
                     const float* __restrict__ dis,
                     float* __restrict__ LP1f, u16* __restrict__ B2) {
    int wib = threadIdx.x >> 6, lane = threadIdx.x & 63;
    int n0 = (blockIdx.x * 4 + wib) * 4;
    int eg = lane >> 3, sub = lane & 7;     // 8 edges x 8 lanes
    const u16* Z = (sub < 4) ? A1 : A2;
    int fq = sub & 3;
    int4 mi = *(const int4*)&indeg[n0];
    int m[4] = {min(mi.x, CAP_), min(mi.y, CAP_), min(mi.z, CAP_), min(mi.w, CAP_)};
    int mmax = max(max(m[0], m[1]), max(m[2], m[3]));
    float ax[4] = {0,0,0,0}, ay[4] = {0,0,0,0}, az[4] = {0,0,0,0}, aw[4] = {0,0,0,0};
    for (int base = 0; base < mmax; base += 8) {
        int e = base + eg;
        int rr[4]; float vm[4];
#pragma unroll
        for (int k = 0; k < 4; ++k) {
            bool v = e < m[k];
            rr[k] = bucket[(size_t)(n0 + k) * CAP_ + (v ? e : 0)];
            vm[k] = v ? 1.0f : 0.0f;
        }
#pragma unroll
        for (int k = 0; k < 4; ++k) {
            int r = (vm[k] != 0.0f) ? rr[k] : 0;
            ushort4 zv = *(const ushort4*)&Z[(size_t)r * 16 + fq * 4];
            ax[k] += vm[k] * bf2f(zv.x); ay[k] += vm[k] * bf2f(zv.y);
            az[k] += vm[k] * bf2f(zv.z); aw[k] += vm[k] * bf2f(zv.w);
        }
    }
#pragma unroll
    for (int off = 8; off < 64; off <<= 1) {
#pragma unroll
        for (int k = 0; k < 4; ++k) {
            ax[k] += __shfl_xor(ax[k], off, 64); ay[k] += __shfl_xor(ay[k], off, 64);
            az[k] += __shfl_xor(az[k], off, 64); aw[k] += __shfl_xor(aw[k], off, 64);
        }
    }
    if (lane < 8) {
#pragma unroll
        for (int k = 0; k < 4; ++k) {
            int n = n0 + k;
            float dn = dis[n];
            if (lane < 4) {
                float4 v = {-dn * ax[k], -dn * ay[k], -dn * az[k], -dn * aw[k]};
                *(float4*)&LP1f[(size_t)n * 16 + fq * 4] = v;
            } else {
                float s = -(dn * dn);
                ushort4 v = {f2bf(s * ax[k]), f2bf(s * ay[k]),
                             f2bf(s * az[k]), f2bf(s * aw[k])};
                *(ushort4*)&B2[(size_t)n * 16 + fq * 4] = v;
            }
        }
    }
}

// ---- 16-wide bf16 gather core, 4 nodes/wave, latency-batched ----
__device__ __forceinline__ void g16core4(const u16* __restrict__ Z,
                                         const int* __restrict__ indeg,
                                         const int* __restrict__ bucket,
                                         int n0, int lane, float4 acc[4]) {
    int eg = lane >> 2, fq = lane & 3;      // 16 edges x 4 lanes
    int4 mi = *(const int4*)&indeg[n0];
    int m[4] = {min(mi.x, CAP_), min(mi.y, CAP_), min(mi.z, CAP_), min(mi.w, CAP_)};
    int mmax = max(max(m[0], m[1]), max(m[2], m[3]));
    float ax[4] = {0,0,0,0}, ay[4] = {0,0,0,0}, az[4] = {0,0,0,0}, aw[4] = {0,0,0,0};
    for (int base = 0; base < mmax; base += 16) {
        int e = base + eg;
        int rr[4]; float vm[4];
#pragma unroll
        for (int k = 0; k < 4; ++k) {
            bool v = e < m[k];
            rr[k] = bucket[(size_t)(n0 + k) * CAP_ + (v ? e : 0)];
            vm[k] = v ? 1.0f : 0.0f;
        }
#pragma unroll
        for (int k = 0; k < 4; ++k) {
            int r = (vm[k] != 0.0f) ? rr[k] : 0;
            ushort4 zv = *(const ushort4*)&Z[(size_t)r * 16 + fq * 4];
            ax[k] += vm[k] * bf2f(zv.x); ay[k] += vm[k] * bf2f(zv.y);
            az[k] += vm[k] * bf2f(zv.z); aw[k] += vm[k] * bf2f(zv.w);
        }
    }
#pragma unroll
    for (int off = 4; off < 64; off <<= 1) {
#pragma unroll
        for (int k = 0; k < 4; ++k) {
            ax[k] += __shfl_xor(ax[k], off, 64); ay[k] += __shfl_xor(ay[k], off, 64);
            az[k] += __shfl_xor(az[k], off, 64); aw[k] += __shfl_xor(aw[k], off, 64);
        }
    }
#pragma unroll
    for (int k = 0; k < 4; ++k) {
        float4 r4 = {ax[k], ay[k], az[k], aw[k]};
        acc[k] = r4;
    }
}

// ---- K5: h = relu(P0 + LP1 - 2*dn*G(B2) - P2 + b1); p0h := h, Hs := bf16(dis*h) ----
__global__ void g16_combine(const u16* __restrict__ B2, const int* __restrict__ indeg,
                            const int* __restrict__ bucket, const float* __restrict__ dis,
                            const float* __restrict__ LP1f, const float* __restrict__ P2f,
                            const float* __restrict__ b1,
                            float* p0h /* in: P0f, out: h */, u16* __restrict__ Hs) {
    int wib = threadIdx.x >> 6, lane = threadIdx.x & 63;
    int n0 = (blockIdx.x * 4 + wib) * 4;
    float4 acc[4];
    g16core4(B2, indeg, bucket, n0, lane, acc);
    if (lane < 4) {
#pragma unroll
        for (int k = 0; k < 4; ++k) {
            int n = n0 + k;
            float dn = dis[n];
            float4 p0 = *(const float4*)&p0h[(size_t)n * 16 + lane * 4];
            float4 lp = *(const float4*)&LP1f[(size_t)n * 16 + lane * 4];
            float4 p2 = *(const float4*)&P2f[(size_t)n * 16 + lane * 4];
            float4 bb = *(const float4*)&b1[lane * 4];
            float4 hv;
            hv.x = fmaxf(p0.x + lp.x - 2.f * dn * acc[k].x - p2.x + bb.x, 0.f);
            hv.y = fmaxf(p0.y + lp.y - 2.f * dn * acc[k].y - p2.y + bb.y, 0.f);
            hv.z = fmaxf(p0.z + lp.z - 2.f * dn * acc[k].z - p2.z + bb.z, 0.f);
            hv.w = fmaxf(p0.w + lp.w - 2.f * dn * acc[k].w - p2.w + bb.w, 0.f);
            *(float4*)&p0h[(size_t)n * 16 + lane * 4] = hv;
            ushort4 hs = {f2bf(dn * hv.x), f2bf(dn * hv.y),
                          f2bf(dn * hv.z), f2bf(dn * hv.w)};
            *(ushort4*)&Hs[(size_t)n * 16 + lane * 4] = hs;
        }
    }
}

// ---- K6: t1 = -dn*G(Hs); T1f (f32), Ts = bf16(dis*t1) ----
__global__ void g16_t1(const u16* __restrict__ Hs, const int* __restrict__ indeg,
                       const int* __restrict__ bucket, const float* __restrict__ dis,
                       float* __restrict__ T1f, u16* __restrict__ Ts) {
    int wib = threadIdx.x >> 6, lane = threadIdx.x & 63;
    int n0 = (blockIdx.x * 4 + wib) * 4;
    float4 acc[4];
    g16core4(Hs, indeg, bucket, n0, lane, acc);
    if (lane < 4) {
#pragma unroll
        for (int k = 0; k < 4; ++k) {
            int n = n0 + k;
            float dn = dis[n];
            float4 t1 = {-dn * acc[k].x, -dn * acc[k].y, -dn * acc[k].z, -dn * acc[k].w};
            *(float4*)&T1f[(size_t)n * 16 + lane * 4] = t1;
            ushort4 ts = {f2bf(dn * t1.x), f2bf(dn * t1.y),
                          f2bf(dn * t1.z), f2bf(dn * t1.w)};
            *(ushort4*)&Ts[(size_t)n * 16 + lane * 4] = ts;
        }
    }
}

// ---- K7: t2 = -2*dn*G(Ts) - h -> T2f (f32) ----
__global__ void g16_t2(const u16* __restrict__ Ts, const int* __restrict__ indeg,
                       const int* __restrict__ bucket, const float* __restrict__ dis,
                       const float* __restrict__ Hf, float* __restrict__ T2f) {
    int wib = threadIdx.x >> 6, lane = threadIdx.x & 63;
    int n0 = (blockIdx.x * 4 + wib) * 4;
    float4 acc[4];
    g16core4(Ts, indeg, bucket, n0, lane, acc);
    if (lane < 4) {
#pragma unroll
        for (int k = 0; k < 4; ++k) {
            int n = n0 + k;
            float dn = dis[n];
            float4 h4 = *(const float4*)&Hf[(size_t)n * 16 + lane * 4];
            float4 t2;
            t2.x = -2.f * dn * acc[k].x - h4.x;
            t2.y = -2.f * dn * acc[k].y - h4.y;
            t2.z = -2.f * dn * acc[k].z - h4.z;
            t2.w = -2.f * dn * acc[k].w - h4.w;
            *(float4*)&T2f[(size_t)n * 16 + lane * 4] = t2;
        }
    }
}

// ---- K8: thread-per-node mm2 + log_softmax (SGPR-broadcast weights) ----
__global__ void __launch_bounds__(256)
mm2_lsm(const float* __restrict__ Hf, const float* __restrict__ T1f,
        const float* __restrict__ T2f, const float* __restrict__ W2,
        const float* __restrict__ b2, float* __restrict__ out) {
    int n = blockIdx.x * 256 + threadIdx.x;
    if (n >= N_) return;
    float act[48];
#pragma unroll
    for (int q = 0; q < 4; ++q)
        *(float4*)&act[q * 4] = *(const float4*)&Hf[(size_t)n * 16 + q * 4];
#pragma unroll
    for (int q = 0; q < 4; ++q)
        *(float4*)&act[16 + q * 4] = *(const float4*)&T1f[(size_t)n * 16 + q * 4];
#pragma unroll
    for (int q = 0; q < 4; ++q)
        *(float4*)&act[32 + q * 4] = *(const float4*)&T2f[(size_t)n * 16 + q * 4];
    float acc[OUT_];
#pragma unroll
    for (int o = 0; o < OUT_; ++o) acc[o] = b2[o];   // uniform -> s_load
#pragma unroll
    for (int j = 0; j < HID_; ++j) {
        float a0 = act[j], a1 = act[16 + j], a2 = act[32 + j];
#pragma unroll
        for (int o = 0; o < OUT_; ++o) {
            acc[o] += a0 * W2[j * OUT_ + o]
                    + a1 * W2[640 + j * OUT_ + o]
                    + a2 * W2[1280 + j * OUT_ + o];   // uniform -> s_load
        }
    }
    float mx = acc[0];
#pragma unroll
    for (int o = 1; o < OUT_; ++o) mx = fmaxf(mx, acc[o]);
    float s = 0.f;
#pragma unroll
    for (int o = 0; o < OUT_; ++o) s += __expf(acc[o] - mx);
    float ls = mx + logf(s);
#pragma unroll
    for (int q = 0; q < 10; ++q) {
        float4 v = {acc[q * 4] - ls, acc[q * 4 + 1] - ls,
                    acc[q * 4 + 2] - ls, acc[q * 4 + 3] - ls};
        *(float4*)&out[(size_t)n * OUT_ + q * 4] = v;
    }
}

// ---------------- launch ----------------

extern "C" void kernel_launch(void* const* d_in, const int* in_sizes, int n_in,
                              void* d_out, int out_size, void* d_ws, size_t ws_size,
                              hipStream_t stream) {
    const float* x  = (const float*)d_in[0];
    const int*   ei = (const int*)d_in[1];
    const float* W1 = (const float*)d_in[2];
    const float* b1 = (const float*)d_in[3];
    const float* W2 = (const float*)d_in[4];
    const float* b2 = (const float*)d_in[5];
    float* out = (float*)d_out;

    const int* row = ei;
    const int* col = ei + E_;

    // workspace (~61.7 MB): [dis][indeg][bucket][pre][REGION]
    char* wp = (char*)d_ws;
    float* dis    = (float*)wp;  wp += 401408;                   // NPAD f32
    int*   indeg  = (int*)wp;    wp += 401408;                   // NPAD i32
    int*   bucket = (int*)wp;    wp += (size_t)N_ * CAP_ * 4;    // 19.2 MB
    u16*   pre    = (u16*)wp;    wp += (size_t)S_ * NPAD_ * 2;   // 12.85 MB
    char*  region = wp;
    // phase 1 (dead after reduce_all):
    u16* pcol = (u16*)region;                          // 256*25000 u16 = 12.8 MB
    u16* prow = (u16*)(region + 12800000);             // 256*25000 u16 = 12.8 MB
    // phase 2 (written by place_proj and later):
    wp = region;
    u16*   A1   = (u16*)wp;   wp += 3211264;           // N*16 bf16 (padded)
    u16*   A2   = (u16*)wp;   wp += 3211264;
    u16*   B2   = (u16*)wp;   wp += 3211264;
    float* P0f  = (float*)wp; wp += 6422528;           // N*16 f32 (padded)
    float* P2f  = (float*)wp; wp += 6422528;
    float* LP1f = (float*)wp; wp += 6422528;

    float* Hf  = P0f;    // h overwrites P0 in-place (same-thread RMW)
    u16*   Hs  = A1;     // A1 dead after g32b
    float* T1f = LP1f;   // LP1f dead after combine
    u16*   Ts  = A2;     // A2 dead after g32b
    float* T2f = P2f;    // P2f dead after combine

    hist2<<<2 * P4_ * S_, 1024, 0, stream>>>(row, col, prow, pcol);
    reduce_all<<<NPAD_ / 1024, 1024, 0, stream>>>(prow, pcol, dis, pre, indeg);
    // grid 3128 = 391*8: bit2-clear slots host placement (s<64), bit2-set host proj
    place_proj<<<3128, 1024, 0, stream>>>(row, col, x, W1, dis, pre,
                                          bucket, P0f, P2f, A1, A2);

    g32b<<<N_ / 16, 256, 0, stream>>>(A1, A2, indeg, bucket, dis, LP1f, B2);
    g16_combine<<<N_ / 16, 256, 0, stream>>>(B2, indeg, bucket, dis, LP1f, P2f, b1,
                                             P0f /*->Hf*/, Hs);
    g16_t1<<<N_ / 16, 256, 0, stream>>>(Hs, indeg, bucket, dis, T1f, Ts);
    g16_t2<<<N_ / 16, 256, 0, stream>>>(Ts, indeg, bucket, dis, Hf, T2f);
    mm2_lsm<<<(N_ + 255) / 256, 256, 0, stream>>>(Hf, T1f, T2f, W2, b2, out);
}